// Round 6
// baseline (1424.354 us; speedup 1.0000x reference)
//
#include <hip/hip_runtime.h>
#include <hip/hip_bf16.h>
#include <stdint.h>

typedef __attribute__((ext_vector_type(16))) float f32x16;
typedef __attribute__((ext_vector_type(8))) int i32x8;

#define M_DIM 8192
#define N_DIM 4096
#define K_DIM 4096
#define NX_INV (1.0f / 33554432.0f)
#define NW_INV (1.0f / 16777216.0f)

// ---------------- fused |x|,|w| sum reduction (one launch), fp64 atomics ----------------
__global__ void absum2_kernel(const float* __restrict__ x, const float* __restrict__ w,
                              double* __restrict__ sums) {
    bool isw = blockIdx.x >= 2048;
    const float4* src = (const float4*)(isw ? w : x);
    int n4  = isw ? (16777216 / 4) : (33554432 / 4);
    int bid = isw ? (blockIdx.x - 2048) : blockIdx.x;
    int nb  = isw ? 1024 : 2048;
    int i = bid * blockDim.x + threadIdx.x;
    int stride = nb * blockDim.x;
    float s = 0.f;
    for (; i < n4; i += stride) {
        float4 v = src[i];
        s += fabsf(v.x) + fabsf(v.y) + fabsf(v.z) + fabsf(v.w);
    }
    #pragma unroll
    for (int off = 32; off >= 1; off >>= 1) s += __shfl_down(s, off, 64);
    __shared__ float wsum[4];
    int lane = threadIdx.x & 63, wid = threadIdx.x >> 6;
    if (lane == 0) wsum[wid] = s;
    __syncthreads();
    if (threadIdx.x == 0) {
        double tot = (double)wsum[0] + (double)wsum[1] + (double)wsum[2] + (double)wsum[3];
        atomicAdd(&sums[isw ? 1 : 0], tot);
    }
}

// ---------------- fp4 e2m1 encode via pre-scaled thresholds ----------------
__device__ __forceinline__ uint32_t enc_nib_t(float x, float t0, float t1, float t2,
                                              float t3, float t4, float t5, float t6) {
    float a = fabsf(x);
    uint32_t idx;
    if (a < t3) idx = (a < t1) ? ((a < t0) ? 0u : 1u) : ((a < t2) ? 2u : 3u);
    else        idx = (a < t5) ? ((a < t4) ? 4u : 5u) : ((a < t6) ? 6u : 7u);
    return idx | ((__float_as_uint(x) >> 31) << 3);
}

// fused quant+pack for X and W (one launch); fragment-major output:
//   unit (mb, kt, l) = 16 B: row mb*32+(l&31), k in [kt*64+(l>>5)*32, +32)
//   P dword offset = ((mb*64 + kt)*64 + l)*4
__global__ void quant2_kernel(const float* __restrict__ X, const float* __restrict__ W,
                              uint32_t* __restrict__ Xp, uint32_t* __restrict__ Wp,
                              const double* __restrict__ sums) {
    __shared__ float4 tile[32 * 64];   // 32 KB, unit-swizzled: [row*64 + (col4 ^ (row&7))]

    bool isw = blockIdx.x >= 4096;
    const float* src_base = isw ? W : X;
    uint32_t* dst = isw ? Wp : Xp;
    float s = (float)(sums[isw ? 1 : 0]) * (isw ? NW_INV : NX_INV);
    int bid = isw ? (blockIdx.x - 4096) : blockIdx.x;

    float t0 = 0.25f * s, t1 = 0.75f * s, t2 = 1.25f * s, t3 = 1.75f * s;
    float t4 = 2.5f * s,  t5 = 3.5f * s,  t6 = 5.0f * s;

    int mb  = bid >> 4;
    int ktg = bid & 15;
    int t = threadIdx.x;

    // ---- coalesced load: 8 passes x (4 rows x 64 float4) ----
    {
        int row0 = t >> 6;
        int col4 = t & 63;
        const float4* src = (const float4*)(src_base + (size_t)(mb * 32 + row0) * K_DIM + ktg * 256) + col4;
        #pragma unroll
        for (int p = 0; p < 8; p++) {
            int row = p * 4 + row0;
            tile[row * 64 + (col4 ^ (row & 7))] = src[(size_t)p * 4 * (K_DIM / 4)];
        }
    }
    __syncthreads();

    // ---- encode: warp w -> kt_local; lane gathers 32 consecutive floats from LDS ----
    int w = t >> 6;
    int l = t & 63;
    int row = l & 31;
    int ub = w * 16 + (l >> 5) * 8;
    uint32_t o[4];
    #pragma unroll
    for (int d = 0; d < 4; d++) {
        float4 f0 = tile[row * 64 + ((ub + 2 * d)     ^ (row & 7))];
        float4 f1 = tile[row * 64 + ((ub + 2 * d + 1) ^ (row & 7))];
        o[d] =  enc_nib_t(f0.x, t0,t1,t2,t3,t4,t5,t6)
             | (enc_nib_t(f0.y, t0,t1,t2,t3,t4,t5,t6) << 4)
             | (enc_nib_t(f0.z, t0,t1,t2,t3,t4,t5,t6) << 8)
             | (enc_nib_t(f0.w, t0,t1,t2,t3,t4,t5,t6) << 12)
             | (enc_nib_t(f1.x, t0,t1,t2,t3,t4,t5,t6) << 16)
             | (enc_nib_t(f1.y, t0,t1,t2,t3,t4,t5,t6) << 20)
             | (enc_nib_t(f1.z, t0,t1,t2,t3,t4,t5,t6) << 24)
             | (enc_nib_t(f1.w, t0,t1,t2,t3,t4,t5,t6) << 28);
    }
    int kt = ktg * 4 + w;
    *(uint4*)(dst + ((size_t)(mb * 64 + kt) * 64 + l) * 4) = make_uint4(o[0], o[1], o[2], o[3]);
}

// ---------------- fp4 MX GEMM, direct-to-register (no LDS, no barriers) ----------------
// Fragment-major layout: a wave's 16B/lane operand unit = 1 KB contiguous in DRAM.
// Block 256x512 (8 waves = 2wm x 4wn), wave tile 128x128 (acc[4][4] f32x16).
// Grid 256 = 1 block/CU. Depth-3 register pipeline, compiler-counted vmcnt.
#define NBLK 256

__device__ __forceinline__ i32x8 dupfrag(uint4 u) {
    i32x8 v;
    v[0] = u.x; v[1] = u.y; v[2] = u.z; v[3] = u.w;   // fp4 consumes 4 regs; duplicate
    v[4] = u.x; v[5] = u.y; v[6] = u.z; v[7] = u.w;   // to cover either half convention
    return v;
}

__global__ __launch_bounds__(512, 2)
void gemm_kernel(const uint32_t* __restrict__ Ap, const uint32_t* __restrict__ Bp,
                 const float* __restrict__ bias, float* __restrict__ C,
                 const double* __restrict__ sums) {
    int bid = blockIdx.x;
    int swz = (bid & 7) * 32 + (bid >> 3);   // 256 blocks, 8 XCDs, bijective
    int bm = (swz >> 3) * 256;               // 32 m-tiles; each XCD: 4 consecutive (A band 2MB, L2-resident)
    int bn = (swz & 7) * 512;                // 8 n-tiles

    int t = threadIdx.x;
    int lane = t & 63;
    int wid = t >> 6;
    int wm = wid >> 2;                       // 0..1
    int wn = wid & 3;                        // 0..3

    // per-m/n fragment base pointers: unit (mb, kt): dword offset (mb*64 + kt)*64*4; +lane*4
    const uint32_t* pA[4];
    const uint32_t* pB[4];
    #pragma unroll
    for (int m = 0; m < 4; m++) pA[m] = Ap + (size_t)((bm >> 5) + wm * 4 + m) * 16384 + lane * 4;
    #pragma unroll
    for (int n = 0; n < 4; n++) pB[n] = Bp + (size_t)((bn >> 5) + wn * 4 + n) * 16384 + lane * 4;

    f32x16 acc[4][4];
    #pragma unroll
    for (int m = 0; m < 4; m++)
        #pragma unroll
        for (int n = 0; n < 4; n++) acc[m][n] = (f32x16)0.f;

    uint4 Sa0[4], Sb0[4], Sa1[4], Sb1[4], Sa2[4], Sb2[4];   // 3 named stages (static idx)

    auto LOADS = [&](uint4* sa, uint4* sb, int kt) {
        #pragma unroll
        for (int m = 0; m < 4; m++) sa[m] = *(const uint4*)(pA[m] + kt * 256);
        #pragma unroll
        for (int n = 0; n < 4; n++) sb[n] = *(const uint4*)(pB[n] + kt * 256);
    };
    auto MFMAS = [&](const uint4* sa, const uint4* sb) {
        i32x8 va[4], vb[4];
        #pragma unroll
        for (int m = 0; m < 4; m++) va[m] = dupfrag(sa[m]);
        #pragma unroll
        for (int n = 0; n < 4; n++) vb[n] = dupfrag(sb[n]);
        __builtin_amdgcn_s_setprio(1);
        #pragma unroll
        for (int m = 0; m < 4; m++)
            #pragma unroll
            for (int n = 0; n < 4; n++)
                acc[m][n] = __builtin_amdgcn_mfma_scale_f32_32x32x64_f8f6f4(
                    va[m], vb[n], acc[m][n], 4, 4, 0, 0x7F7F7F7F, 0, 0x7F7F7F7F);
        __builtin_amdgcn_s_setprio(0);
    };

    LOADS(Sa0, Sb0, 0);
    LOADS(Sa1, Sb1, 1);
    LOADS(Sa2, Sb2, 2);
    for (int kt = 0; kt < 63; kt += 3) {       // kt = 0,3,...,60 (21 iters, MFMA 0..62)
        MFMAS(Sa0, Sb0);
        if (kt + 3 < 64) LOADS(Sa0, Sb0, kt + 3);
        MFMAS(Sa1, Sb1);
        if (kt + 4 < 64) LOADS(Sa1, Sb1, kt + 4);
        MFMAS(Sa2, Sb2);
        if (kt + 5 < 64) LOADS(Sa2, Sb2, kt + 5);
    }
    MFMAS(Sa0, Sb0);                           // kt = 63 (loaded at iter kt=60)

    float scale = (float)((sums[0] * (1.0 / 33554432.0)) * (sums[1] * (1.0 / 16777216.0)));

    // C/D 32x32 layout: col=lane&31, row=(i&3)+8*(i>>2)+4*(lane>>5)
    int colb = bn + wn * 128 + (lane & 31);
    int rowb = bm + wm * 128 + ((lane >> 5) << 2);
    #pragma unroll
    for (int m = 0; m < 4; m++)
        #pragma unroll
        for (int n = 0; n < 4; n++) {
            int col = colb + n * 32;
            float bv = bias[col];
            #pragma unroll
            for (int i = 0; i < 16; i++) {
                int row = rowb + m * 32 + (i & 3) + ((i >> 2) << 3);
                __builtin_nontemporal_store(acc[m][n][i] * scale + bv,
                                            &C[(size_t)row * N_DIM + col]);
            }
        }
}

extern "C" void kernel_launch(void* const* d_in, const int* in_sizes, int n_in,
                              void* d_out, int out_size, void* d_ws, size_t ws_size,
                              hipStream_t stream) {
    const float* x    = (const float*)d_in[0];   // [4,2048,4096]
    const float* w    = (const float*)d_in[1];   // [4096,4096]
    const float* bias = (const float*)d_in[2];   // [4096]
    float* out = (float*)d_out;                  // [4,2048,4096] fp32

    double* sums = (double*)d_ws;
    uint32_t* Xp = (uint32_t*)((char*)d_ws + 1024);   // 16 MB packed fp4, fragment-major
    uint32_t* Wp = Xp + (size_t)256 * 64 * 64 * 4;    // 8 MB

    hipMemsetAsync(d_ws, 0, 1024, stream);
    absum2_kernel<<<3072, 256, 0, stream>>>(x, w, sums);
    quant2_kernel<<<6144, 256, 0, stream>>>(x, w, Xp, Wp, sums);
    gemm_kernel<<<NBLK, 512, 0, stream>>>(Xp, Wp, bias, out, sums);
}

// Round 7
// 443.888 us; speedup vs baseline: 3.2088x; 3.2088x over previous
//
#include <hip/hip_runtime.h>
#include <hip/hip_bf16.h>
#include <stdint.h>

typedef __attribute__((ext_vector_type(16))) float f32x16;
typedef __attribute__((ext_vector_type(8))) int i32x8;

#define M_DIM 8192
#define N_DIM 4096
#define K_DIM 4096
#define NX_INV (1.0f / 33554432.0f)
#define NW_INV (1.0f / 16777216.0f)

// ---------------- fused |x|,|w| sum reduction (one launch), fp64 atomics ----------------
__global__ void absum2_kernel(const float* __restrict__ x, const float* __restrict__ w,
                              double* __restrict__ sums) {
    bool isw = blockIdx.x >= 2048;
    const float4* src = (const float4*)(isw ? w : x);
    int n4  = isw ? (16777216 / 4) : (33554432 / 4);
    int bid = isw ? (blockIdx.x - 2048) : blockIdx.x;
    int nb  = isw ? 1024 : 2048;
    int i = bid * blockDim.x + threadIdx.x;
    int stride = nb * blockDim.x;
    float s = 0.f;
    for (; i < n4; i += stride) {
        float4 v = src[i];
        s += fabsf(v.x) + fabsf(v.y) + fabsf(v.z) + fabsf(v.w);
    }
    #pragma unroll
    for (int off = 32; off >= 1; off >>= 1) s += __shfl_down(s, off, 64);
    __shared__ float wsum[4];
    int lane = threadIdx.x & 63, wid = threadIdx.x >> 6;
    if (lane == 0) wsum[wid] = s;
    __syncthreads();
    if (threadIdx.x == 0) {
        double tot = (double)wsum[0] + (double)wsum[1] + (double)wsum[2] + (double)wsum[3];
        atomicAdd(&sums[isw ? 1 : 0], tot);
    }
}

// ---------------- fp4 e2m1 encode via pre-scaled thresholds ----------------
__device__ __forceinline__ uint32_t enc_nib_t(float x, float t0, float t1, float t2,
                                              float t3, float t4, float t5, float t6) {
    float a = fabsf(x);
    uint32_t idx;
    if (a < t3) idx = (a < t1) ? ((a < t0) ? 0u : 1u) : ((a < t2) ? 2u : 3u);
    else        idx = (a < t5) ? ((a < t4) ? 4u : 5u) : ((a < t6) ? 6u : 7u);
    return idx | ((__float_as_uint(x) >> 31) << 3);
}

// fused quant+pack for X and W (one launch); fragment-major output:
//   unit (mb, kt, l) = 16 B: row mb*32+(l&31), k in [kt*64+(l>>5)*32, +32)
//   P dword offset = ((mb*64 + kt)*64 + l)*4
__global__ void quant2_kernel(const float* __restrict__ X, const float* __restrict__ W,
                              uint32_t* __restrict__ Xp, uint32_t* __restrict__ Wp,
                              const double* __restrict__ sums) {
    __shared__ float4 tile[32 * 64];   // 32 KB, unit-swizzled: [row*64 + (col4 ^ (row&7))]

    bool isw = blockIdx.x >= 4096;
    const float* src_base = isw ? W : X;
    uint32_t* dst = isw ? Wp : Xp;
    float s = (float)(sums[isw ? 1 : 0]) * (isw ? NW_INV : NX_INV);
    int bid = isw ? (blockIdx.x - 4096) : blockIdx.x;

    float t0 = 0.25f * s, t1 = 0.75f * s, t2 = 1.25f * s, t3 = 1.75f * s;
    float t4 = 2.5f * s,  t5 = 3.5f * s,  t6 = 5.0f * s;

    int mb  = bid >> 4;
    int ktg = bid & 15;
    int t = threadIdx.x;

    {
        int row0 = t >> 6;
        int col4 = t & 63;
        const float4* src = (const float4*)(src_base + (size_t)(mb * 32 + row0) * K_DIM + ktg * 256) + col4;
        #pragma unroll
        for (int p = 0; p < 8; p++) {
            int row = p * 4 + row0;
            tile[row * 64 + (col4 ^ (row & 7))] = src[(size_t)p * 4 * (K_DIM / 4)];
        }
    }
    __syncthreads();

    int w = t >> 6;
    int l = t & 63;
    int row = l & 31;
    int ub = w * 16 + (l >> 5) * 8;
    uint32_t o[4];
    #pragma unroll
    for (int d = 0; d < 4; d++) {
        float4 f0 = tile[row * 64 + ((ub + 2 * d)     ^ (row & 7))];
        float4 f1 = tile[row * 64 + ((ub + 2 * d + 1) ^ (row & 7))];
        o[d] =  enc_nib_t(f0.x, t0,t1,t2,t3,t4,t5,t6)
             | (enc_nib_t(f0.y, t0,t1,t2,t3,t4,t5,t6) << 4)
             | (enc_nib_t(f0.z, t0,t1,t2,t3,t4,t5,t6) << 8)
             | (enc_nib_t(f0.w, t0,t1,t2,t3,t4,t5,t6) << 12)
             | (enc_nib_t(f1.x, t0,t1,t2,t3,t4,t5,t6) << 16)
             | (enc_nib_t(f1.y, t0,t1,t2,t3,t4,t5,t6) << 20)
             | (enc_nib_t(f1.z, t0,t1,t2,t3,t4,t5,t6) << 24)
             | (enc_nib_t(f1.w, t0,t1,t2,t3,t4,t5,t6) << 28);
    }
    int kt = ktg * 4 + w;
    *(uint4*)(dst + ((size_t)(mb * 64 + kt) * 64 + l) * 4) = make_uint4(o[0], o[1], o[2], o[3]);
}

// ---------------- fp4 MX GEMM, direct-to-register (no LDS, no barriers) ----------------
// Fragment-major: a wave's operand unit (64 lanes x 16B) = 1 KB contiguous in DRAM.
// Block 256x256 = 4 waves (2x2), wave tile 128x128 (acc[4][4] f32x16 = 256 regs).
// 1 wave/SIMD (512-reg budget, launch_bounds(256,1)); grid 512 = 2 rounds/CU.
// Depth-2 register pipeline; operand sharing (2x A, 2x B) dedup'd by L1.
#define NWG 512

__device__ __forceinline__ i32x8 dupfrag(uint4 u) {
    i32x8 v;
    v[0] = u.x; v[1] = u.y; v[2] = u.z; v[3] = u.w;   // fp4 consumes 4 regs; duplicate
    v[4] = u.x; v[5] = u.y; v[6] = u.z; v[7] = u.w;   // to cover either half convention
    return v;
}

__global__ __launch_bounds__(256, 1)
void gemm_kernel(const uint32_t* __restrict__ Ap, const uint32_t* __restrict__ Bp,
                 const float* __restrict__ bias, float* __restrict__ C,
                 const double* __restrict__ sums) {
    int bid = blockIdx.x;
    int swz = (bid & 7) * 64 + (bid >> 3);   // 512 blocks, 8 XCDs, bijective
    int bm = (swz >> 4) * 256;               // 32 m-tiles; per-XCD A band = 1024 rows (2 MB, L2-fit)
    int bn = (swz & 15) * 256;               // 16 n-tiles

    int lane = threadIdx.x & 63;
    int wid = threadIdx.x >> 6;
    int wm = wid >> 1;                       // 0..1
    int wn = wid & 1;                        // 0..1

    // fragment base pointers: unit (mb, kt) at dword offset (mb*64 + kt)*256; lane*4
    const uint32_t* pA[4];
    const uint32_t* pB[4];
    #pragma unroll
    for (int m = 0; m < 4; m++) pA[m] = Ap + (size_t)((bm >> 5) + wm * 4 + m) * 16384 + lane * 4;
    #pragma unroll
    for (int n = 0; n < 4; n++) pB[n] = Bp + (size_t)((bn >> 5) + wn * 4 + n) * 16384 + lane * 4;

    f32x16 acc[4][4];
    #pragma unroll
    for (int m = 0; m < 4; m++)
        #pragma unroll
        for (int n = 0; n < 4; n++) acc[m][n] = (f32x16)0.f;

    uint4 Sa0[4], Sb0[4], Sa1[4], Sb1[4];    // 2 named stages, static indexing

    auto LOADS = [&](uint4* sa, uint4* sb, int kt) {
        #pragma unroll
        for (int m = 0; m < 4; m++) sa[m] = *(const uint4*)(pA[m] + kt * 256);
        #pragma unroll
        for (int n = 0; n < 4; n++) sb[n] = *(const uint4*)(pB[n] + kt * 256);
    };
    auto MFMAS = [&](const uint4* sa, const uint4* sb) {
        i32x8 vb[4];
        #pragma unroll
        for (int n = 0; n < 4; n++) vb[n] = dupfrag(sb[n]);
        __builtin_amdgcn_s_setprio(1);
        #pragma unroll
        for (int m = 0; m < 4; m++) {
            i32x8 va = dupfrag(sa[m]);
            #pragma unroll
            for (int n = 0; n < 4; n++)
                acc[m][n] = __builtin_amdgcn_mfma_scale_f32_32x32x64_f8f6f4(
                    va, vb[n], acc[m][n], 4, 4, 0, 0x7F7F7F7F, 0, 0x7F7F7F7F);
        }
        __builtin_amdgcn_s_setprio(0);
    };

    LOADS(Sa0, Sb0, 0);
    LOADS(Sa1, Sb1, 1);
    for (int kt = 0; kt < 62; kt += 2) {
        MFMAS(Sa0, Sb0);
        LOADS(Sa0, Sb0, kt + 2);
        MFMAS(Sa1, Sb1);
        LOADS(Sa1, Sb1, kt + 3);
    }
    MFMAS(Sa0, Sb0);
    MFMAS(Sa1, Sb1);

    float scale = (float)((sums[0] * (1.0 / 33554432.0)) * (sums[1] * (1.0 / 16777216.0)));

    // C/D 32x32 layout: col=lane&31, row=(i&3)+8*(i>>2)+4*(lane>>5)
    int colb = bn + wn * 128 + (lane & 31);
    int rowb = bm + wm * 128 + ((lane >> 5) << 2);
    #pragma unroll
    for (int m = 0; m < 4; m++)
        #pragma unroll
        for (int n = 0; n < 4; n++) {
            int col = colb + n * 32;
            float bv = bias[col];
            #pragma unroll
            for (int i = 0; i < 16; i++) {
                int row = rowb + m * 32 + (i & 3) + ((i >> 2) << 3);
                __builtin_nontemporal_store(acc[m][n][i] * scale + bv,
                                            &C[(size_t)row * N_DIM + col]);
            }
        }
}

extern "C" void kernel_launch(void* const* d_in, const int* in_sizes, int n_in,
                              void* d_out, int out_size, void* d_ws, size_t ws_size,
                              hipStream_t stream) {
    const float* x    = (const float*)d_in[0];   // [4,2048,4096]
    const float* w    = (const float*)d_in[1];   // [4096,4096]
    const float* bias = (const float*)d_in[2];   // [4096]
    float* out = (float*)d_out;                  // [4,2048,4096] fp32

    double* sums = (double*)d_ws;
    uint32_t* Xp = (uint32_t*)((char*)d_ws + 1024);   // 16 MB packed fp4, fragment-major
    uint32_t* Wp = Xp + (size_t)256 * 64 * 64 * 4;    // 8 MB

    hipMemsetAsync(d_ws, 0, 1024, stream);
    absum2_kernel<<<3072, 256, 0, stream>>>(x, w, sums);
    quant2_kernel<<<6144, 256, 0, stream>>>(x, w, Xp, Wp, sums);
    gemm_kernel<<<NWG, 256, 0, stream>>>(Xp, Wp, bias, out, sums);
}

// Round 8
// 183.946 us; speedup vs baseline: 7.7433x; 2.4131x over previous
//
#include <hip/hip_runtime.h>
#include <hip/hip_bf16.h>
#include <stdint.h>

typedef __attribute__((ext_vector_type(16))) float f32x16;
typedef __attribute__((ext_vector_type(8))) int i32x8;

#define M_DIM 8192
#define N_DIM 4096
#define K_DIM 4096
#define NX_INV (1.0f / 33554432.0f)
#define NW_INV (1.0f / 16777216.0f)

// ---------------- fused |x|,|w| sum reduction (one launch), fp64 atomics ----------------
__global__ void absum2_kernel(const float* __restrict__ x, const float* __restrict__ w,
                              double* __restrict__ sums) {
    bool isw = blockIdx.x >= 2048;
    const float4* src = (const float4*)(isw ? w : x);
    int n4  = isw ? (16777216 / 4) : (33554432 / 4);
    int bid = isw ? (blockIdx.x - 2048) : blockIdx.x;
    int nb  = isw ? 1024 : 2048;
    int i = bid * blockDim.x + threadIdx.x;
    int stride = nb * blockDim.x;
    float s = 0.f;
    for (; i < n4; i += stride) {
        float4 v = src[i];
        s += fabsf(v.x) + fabsf(v.y) + fabsf(v.z) + fabsf(v.w);
    }
    #pragma unroll
    for (int off = 32; off >= 1; off >>= 1) s += __shfl_down(s, off, 64);
    __shared__ float wsum[4];
    int lane = threadIdx.x & 63, wid = threadIdx.x >> 6;
    if (lane == 0) wsum[wid] = s;
    __syncthreads();
    if (threadIdx.x == 0) {
        double tot = (double)wsum[0] + (double)wsum[1] + (double)wsum[2] + (double)wsum[3];
        atomicAdd(&sums[isw ? 1 : 0], tot);
    }
}

// ---------------- fp4 e2m1 encode via pre-scaled thresholds ----------------
__device__ __forceinline__ uint32_t enc_nib_t(float x, float t0, float t1, float t2,
                                              float t3, float t4, float t5, float t6) {
    float a = fabsf(x);
    uint32_t idx;
    if (a < t3) idx = (a < t1) ? ((a < t0) ? 0u : 1u) : ((a < t2) ? 2u : 3u);
    else        idx = (a < t5) ? ((a < t4) ? 4u : 5u) : ((a < t6) ? 6u : 7u);
    return idx | ((__float_as_uint(x) >> 31) << 3);
}

// fused quant+pack for X and W (one launch); fragment-major output:
//   unit (mb, kt, l) = 16 B: row mb*32+(l&31), k in [kt*64+(l>>5)*32, +32)
//   P dword offset = ((mb*64 + kt)*64 + l)*4
__global__ void quant2_kernel(const float* __restrict__ X, const float* __restrict__ W,
                              uint32_t* __restrict__ Xp, uint32_t* __restrict__ Wp,
                              const double* __restrict__ sums) {
    __shared__ float4 tile[32 * 64];   // 32 KB, unit-swizzled: [row*64 + (col4 ^ (row&7))]

    bool isw = blockIdx.x >= 4096;
    const float* src_base = isw ? W : X;
    uint32_t* dst = isw ? Wp : Xp;
    float s = (float)(sums[isw ? 1 : 0]) * (isw ? NW_INV : NX_INV);
    int bid = isw ? (blockIdx.x - 4096) : blockIdx.x;

    float t0 = 0.25f * s, t1 = 0.75f * s, t2 = 1.25f * s, t3 = 1.75f * s;
    float t4 = 2.5f * s,  t5 = 3.5f * s,  t6 = 5.0f * s;

    int mb  = bid >> 4;
    int ktg = bid & 15;
    int t = threadIdx.x;

    {
        int row0 = t >> 6;
        int col4 = t & 63;
        const float4* src = (const float4*)(src_base + (size_t)(mb * 32 + row0) * K_DIM + ktg * 256) + col4;
        #pragma unroll
        for (int p = 0; p < 8; p++) {
            int row = p * 4 + row0;
            tile[row * 64 + (col4 ^ (row & 7))] = src[(size_t)p * 4 * (K_DIM / 4)];
        }
    }
    __syncthreads();

    int w = t >> 6;
    int l = t & 63;
    int row = l & 31;
    int ub = w * 16 + (l >> 5) * 8;
    uint32_t o[4];
    #pragma unroll
    for (int d = 0; d < 4; d++) {
        float4 f0 = tile[row * 64 + ((ub + 2 * d)     ^ (row & 7))];
        float4 f1 = tile[row * 64 + ((ub + 2 * d + 1) ^ (row & 7))];
        o[d] =  enc_nib_t(f0.x, t0,t1,t2,t3,t4,t5,t6)
             | (enc_nib_t(f0.y, t0,t1,t2,t3,t4,t5,t6) << 4)
             | (enc_nib_t(f0.z, t0,t1,t2,t3,t4,t5,t6) << 8)
             | (enc_nib_t(f0.w, t0,t1,t2,t3,t4,t5,t6) << 12)
             | (enc_nib_t(f1.x, t0,t1,t2,t3,t4,t5,t6) << 16)
             | (enc_nib_t(f1.y, t0,t1,t2,t3,t4,t5,t6) << 20)
             | (enc_nib_t(f1.z, t0,t1,t2,t3,t4,t5,t6) << 24)
             | (enc_nib_t(f1.w, t0,t1,t2,t3,t4,t5,t6) << 28);
    }
    int kt = ktg * 4 + w;
    *(uint4*)(dst + ((size_t)(mb * 64 + kt) * 64 + l) * 4) = make_uint4(o[0], o[1], o[2], o[3]);
}

// ---------------- fp4 MX GEMM, direct-to-register (no LDS, no barriers) ----------------
// Fragment-major: a wave's operand unit (64 lanes x 16B) = 1 KB contiguous in DRAM.
// Block 256x256 = 4 waves (2x2), wave tile 128x128 (acc = 16 x f32x16 in AGPRs).
// 1 wave/SIMD (launch_bounds(256,1)); grid 512 = 2 rounds/CU.
// Depth-3 register pipeline with FULLY NAMED stage scalars (rule #20: no arrays,
// no pointer-passed lambdas -> guaranteed SROA, no scratch).
#define NWG 512

__device__ __forceinline__ i32x8 dupfrag(uint4 u) {
    i32x8 v;
    v[0] = u.x; v[1] = u.y; v[2] = u.z; v[3] = u.w;   // fp4 consumes 4 regs; duplicate
    v[4] = u.x; v[5] = u.y; v[6] = u.z; v[7] = u.w;   // to cover either half convention
    return v;
}

#define LOADST(S, kt) do {                                      \
    S##a0 = *(const uint4*)(pA0 + (size_t)(kt) * 256);          \
    S##a1 = *(const uint4*)(pA1 + (size_t)(kt) * 256);          \
    S##a2 = *(const uint4*)(pA2 + (size_t)(kt) * 256);          \
    S##a3 = *(const uint4*)(pA3 + (size_t)(kt) * 256);          \
    S##b0 = *(const uint4*)(pB0 + (size_t)(kt) * 256);          \
    S##b1 = *(const uint4*)(pB1 + (size_t)(kt) * 256);          \
    S##b2 = *(const uint4*)(pB2 + (size_t)(kt) * 256);          \
    S##b3 = *(const uint4*)(pB3 + (size_t)(kt) * 256);          \
} while (0)

#define MFMA_ROW(VA, B0, B1, B2, B3, C0, C1, C2, C3) do {                         \
    i32x8 va_ = dupfrag(VA);                                                      \
    C0 = __builtin_amdgcn_mfma_scale_f32_32x32x64_f8f6f4(va_, B0, C0, 4, 4, 0, 0x7F7F7F7F, 0, 0x7F7F7F7F); \
    C1 = __builtin_amdgcn_mfma_scale_f32_32x32x64_f8f6f4(va_, B1, C1, 4, 4, 0, 0x7F7F7F7F, 0, 0x7F7F7F7F); \
    C2 = __builtin_amdgcn_mfma_scale_f32_32x32x64_f8f6f4(va_, B2, C2, 4, 4, 0, 0x7F7F7F7F, 0, 0x7F7F7F7F); \
    C3 = __builtin_amdgcn_mfma_scale_f32_32x32x64_f8f6f4(va_, B3, C3, 4, 4, 0, 0x7F7F7F7F, 0, 0x7F7F7F7F); \
} while (0)

#define MFMA_TILE(S) do {                                                         \
    i32x8 vb0_ = dupfrag(S##b0), vb1_ = dupfrag(S##b1);                           \
    i32x8 vb2_ = dupfrag(S##b2), vb3_ = dupfrag(S##b3);                           \
    __builtin_amdgcn_s_setprio(1);                                                \
    MFMA_ROW(S##a0, vb0_, vb1_, vb2_, vb3_, acc00, acc01, acc02, acc03);          \
    MFMA_ROW(S##a1, vb0_, vb1_, vb2_, vb3_, acc10, acc11, acc12, acc13);          \
    MFMA_ROW(S##a2, vb0_, vb1_, vb2_, vb3_, acc20, acc21, acc22, acc23);          \
    MFMA_ROW(S##a3, vb0_, vb1_, vb2_, vb3_, acc30, acc31, acc32, acc33);          \
    __builtin_amdgcn_s_setprio(0);                                                \
} while (0)

#define EPI(ACC, MM, NN) do {                                                     \
    int col_ = colb + (NN) * 32;                                                  \
    float bv_ = bias[col_];                                                       \
    _Pragma("unroll")                                                             \
    for (int i = 0; i < 16; i++) {                                                \
        int row_ = rowb + (MM) * 32 + (i & 3) + ((i >> 2) << 3);                  \
        __builtin_nontemporal_store(ACC[i] * scale + bv_,                         \
                                    &C[(size_t)row_ * N_DIM + col_]);             \
    }                                                                             \
} while (0)

__global__ __launch_bounds__(256, 1)
void gemm_kernel(const uint32_t* __restrict__ Ap, const uint32_t* __restrict__ Bp,
                 const float* __restrict__ bias, float* __restrict__ C,
                 const double* __restrict__ sums) {
    int bid = blockIdx.x;
    int swz = (bid & 7) * 64 + (bid >> 3);   // 512 blocks, 8 XCDs, bijective
    int bm = (swz >> 4) * 256;               // 32 m-tiles; per-XCD A band = 1024 rows (2 MB)
    int bn = (swz & 15) * 256;               // 16 n-tiles

    int lane = threadIdx.x & 63;
    int wid = threadIdx.x >> 6;
    int wm = wid >> 1;                       // 0..1
    int wn = wid & 1;                        // 0..1

    // fragment base pointers (named): unit (mb, kt) at dword offset (mb*64+kt)*256
    const uint32_t* pA0 = Ap + (size_t)((bm >> 5) + wm * 4 + 0) * 16384 + lane * 4;
    const uint32_t* pA1 = Ap + (size_t)((bm >> 5) + wm * 4 + 1) * 16384 + lane * 4;
    const uint32_t* pA2 = Ap + (size_t)((bm >> 5) + wm * 4 + 2) * 16384 + lane * 4;
    const uint32_t* pA3 = Ap + (size_t)((bm >> 5) + wm * 4 + 3) * 16384 + lane * 4;
    const uint32_t* pB0 = Bp + (size_t)((bn >> 5) + wn * 4 + 0) * 16384 + lane * 4;
    const uint32_t* pB1 = Bp + (size_t)((bn >> 5) + wn * 4 + 1) * 16384 + lane * 4;
    const uint32_t* pB2 = Bp + (size_t)((bn >> 5) + wn * 4 + 2) * 16384 + lane * 4;
    const uint32_t* pB3 = Bp + (size_t)((bn >> 5) + wn * 4 + 3) * 16384 + lane * 4;

    f32x16 acc00 = (f32x16)0.f, acc01 = (f32x16)0.f, acc02 = (f32x16)0.f, acc03 = (f32x16)0.f;
    f32x16 acc10 = (f32x16)0.f, acc11 = (f32x16)0.f, acc12 = (f32x16)0.f, acc13 = (f32x16)0.f;
    f32x16 acc20 = (f32x16)0.f, acc21 = (f32x16)0.f, acc22 = (f32x16)0.f, acc23 = (f32x16)0.f;
    f32x16 acc30 = (f32x16)0.f, acc31 = (f32x16)0.f, acc32 = (f32x16)0.f, acc33 = (f32x16)0.f;

    uint4 S0a0, S0a1, S0a2, S0a3, S0b0, S0b1, S0b2, S0b3;
    uint4 S1a0, S1a1, S1a2, S1a3, S1b0, S1b1, S1b2, S1b3;
    uint4 S2a0, S2a1, S2a2, S2a3, S2b0, S2b1, S2b2, S2b3;

    LOADST(S0, 0);
    LOADST(S1, 1);
    LOADST(S2, 2);
    for (int kt = 0; kt < 63; kt += 3) {     // kt = 0,3,...,60 (21 iters)
        MFMA_TILE(S0);
        if (kt + 3 < 64) LOADST(S0, kt + 3);
        MFMA_TILE(S1);
        if (kt + 4 < 64) LOADST(S1, kt + 4);
        MFMA_TILE(S2);
        if (kt + 5 < 64) LOADST(S2, kt + 5);
    }
    MFMA_TILE(S0);                           // kt = 63

    float scale = (float)((sums[0] * (1.0 / 33554432.0)) * (sums[1] * (1.0 / 16777216.0)));

    // C/D 32x32 layout: col=lane&31, row=(i&3)+8*(i>>2)+4*(lane>>5)
    int colb = bn + wn * 128 + (lane & 31);
    int rowb = bm + wm * 128 + ((lane >> 5) << 2);
    EPI(acc00, 0, 0); EPI(acc01, 0, 1); EPI(acc02, 0, 2); EPI(acc03, 0, 3);
    EPI(acc10, 1, 0); EPI(acc11, 1, 1); EPI(acc12, 1, 2); EPI(acc13, 1, 3);
    EPI(acc20, 2, 0); EPI(acc21, 2, 1); EPI(acc22, 2, 2); EPI(acc23, 2, 3);
    EPI(acc30, 3, 0); EPI(acc31, 3, 1); EPI(acc32, 3, 2); EPI(acc33, 3, 3);
}

extern "C" void kernel_launch(void* const* d_in, const int* in_sizes, int n_in,
                              void* d_out, int out_size, void* d_ws, size_t ws_size,
                              hipStream_t stream) {
    const float* x    = (const float*)d_in[0];   // [4,2048,4096]
    const float* w    = (const float*)d_in[1];   // [4096,4096]
    const float* bias = (const float*)d_in[2];   // [4096]
    float* out = (float*)d_out;                  // [4,2048,4096] fp32

    double* sums = (double*)d_ws;
    uint32_t* Xp = (uint32_t*)((char*)d_ws + 1024);   // 16 MB packed fp4, fragment-major
    uint32_t* Wp = Xp + (size_t)256 * 64 * 64 * 4;    // 8 MB

    hipMemsetAsync(d_ws, 0, 1024, stream);
    absum2_kernel<<<3072, 256, 0, stream>>>(x, w, sums);
    quant2_kernel<<<6144, 256, 0, stream>>>(x, w, Xp, Wp, sums);
    gemm_kernel<<<NWG, 256, 0, stream>>>(Xp, Wp, bias, out, sums);
}